// Round 9
// baseline (67.509 us; speedup 1.0000x reference)
//
#include <hip/hip_runtime.h>

#define N_IMG 32
#define H_IMG 224
#define W_IMG 224

// Fused grid, heavy scales first:
// S=16: [0, 25)        32*14*14 threads  (last block partial)
// S=8 : [25, 123)      32*28*28
// S=4 : [123, 515)     32*56*56
// S=2 : [515, 2083)    32*112*112
// S=1 : [2083, 3651)   32*224*56 vec4-threads (4 outputs each)
#define BS16_END 25
#define BS8_END 123
#define BS4_END 515
#define BS2_END 2083
#define NBLK_TOTAL 3651

__device__ __forceinline__ int reflect_idx(int i, int n) {
    if (i < 0) return -i;
    if (i >= n) return 2 * n - 2 - i;
    return i;
}

// bin = floor(atan2(gx,gy)/pi*9) mod 9 without atan2: direction-only sector count.
__device__ __forceinline__ int bin_from_g(float gx, float gy) {
    float u = gx * __builtin_copysignf(1.0f, gy);
    float w = __builtin_fabsf(gy);
    const float T[9] = {-5.6712818f, -1.7320508f, -0.83909963f, -0.36397023f,
                        0.0f, 0.36397023f, 0.83909963f, 1.7320508f, 5.6712818f};
    int c = 0;
    #pragma unroll
    for (int k = 0; k < 9; ++k) c += (u >= T[k] * w) ? 1 : 0;
    int b = c + 4;
    return (b >= 9) ? b - 9 : b;
}

// ---------------- s=1, four outputs per thread ----------------
__device__ __forceinline__ void s1_body4(int rel_bid,
    const float* __restrict__ imgs, const float* __restrict__ mask,
    const float* __restrict__ pred,
    const float* spwT, const float* spb, const float* sA, const float* sB,
    float Cc, float& local, float& mlocal)
{
    constexpr int WsV = W_IMG / 4;   // 56
    int vt = rel_bid * 256 + (int)threadIdx.x;
    int jv = vt % WsV;
    int t  = vt / WsV;
    int i  = t % H_IMG;
    int n  = t / H_IMG;
    int j0 = jv * 4;

    constexpr size_t cstride = (size_t)H_IMG * W_IMG;
    float4 mv = *(const float4*)(mask + (size_t)n * cstride + (size_t)i * W_IMG + j0);

    int y0 = reflect_idx(i - 1, H_IMG), y2 = reflect_idx(i + 1, H_IMG);
    int xl = reflect_idx(j0 - 1, W_IMG);
    int xr = reflect_idx(j0 + 4, W_IMG);

    float d2[4] = {0.0f, 0.0f, 0.0f, 0.0f};
    #pragma unroll
    for (int c = 0; c < 3; ++c) {
        const float* im = imgs + (size_t)(n * 3 + c) * cstride;
        const float* q0 = im + (size_t)y0 * W_IMG;
        const float* q1 = im + (size_t)i  * W_IMG;
        const float* q2 = im + (size_t)y2 * W_IMG;

        // img loads first (oldest in queue -> sobel waits only on these)
        float r0[6], r1[6], r2[6];
        float4 f;
        r0[0] = q0[xl]; f = *(const float4*)(q0 + j0);
        r0[1] = f.x; r0[2] = f.y; r0[3] = f.z; r0[4] = f.w; r0[5] = q0[xr];
        r1[0] = q1[xl]; f = *(const float4*)(q1 + j0);
        r1[1] = f.x; r1[2] = f.y; r1[3] = f.z; r1[4] = f.w; r1[5] = q1[xr];
        r2[0] = q2[xl]; f = *(const float4*)(q2 + j0);
        r2[1] = f.x; r2[2] = f.y; r2[3] = f.z; r2[4] = f.w; r2[5] = q2[xr];

        // stage 9 float4 preds: each is a contiguous 1KB wave-segment
        const float* pr = pred + ((size_t)(n * 27 + c * 9) * H_IMG + i) * W_IMG + j0;
        float4 p[9];
        #pragma unroll
        for (int o = 0; o < 9; ++o) p[o] = *(const float4*)(pr + o * cstride);

        #pragma unroll
        for (int v = 0; v < 4; ++v) {
            float gx = (r0[v] - r0[v + 2]) + 2.0f * (r1[v] - r1[v + 2]) + (r2[v] - r2[v + 2]);
            float gy = (r0[v] - r2[v]) + 2.0f * (r0[v + 1] - r2[v + 1]) + (r0[v + 2] - r2[v + 2]);
            float mag = sqrtf(gx * gx + gy * gy);
            int bn = bin_from_g(gx, gy);
            float nrm2 = fmaf(mag, fmaf(mag, sA[bn], 2.0f * sB[bn]), Cc);
            float inv = 1.0f / fmaxf(sqrtf(nrm2), 1e-12f);
            #pragma unroll
            for (int o = 0; o < 9; ++o) {
                float h = fmaf(spwT[bn * 9 + o], mag, spb[o]) * inv;
                float pv = (v == 0) ? p[o].x : (v == 1) ? p[o].y : (v == 2) ? p[o].z : p[o].w;
                float dd = pv - h;
                d2[v] += dd * dd;
            }
        }
    }

    local  = (mv.x * d2[0] + mv.y * d2[1] + mv.z * d2[2] + mv.w * d2[3]) * (1.0f / 27.0f);
    mlocal = (mv.x + mv.y) + (mv.z + mv.w);   // sum over s=1 == sum(mask)
}

// ---------------- generic S>=2, one output per thread ----------------
template <int S>
__device__ __forceinline__ void scale_body(int rel_bid,
    const float* __restrict__ imgs, const float* __restrict__ mask,
    const float* __restrict__ pred,
    const float* spwT, const float* spb, const float* sA, const float* sB,
    float Cc, float& local)
{
    constexpr int Hs = H_IMG / S, Ws = W_IMG / S;
    int vt = rel_bid * 256 + (int)threadIdx.x;
    if (vt >= N_IMG * Hs * Ws) return;
    int j = vt % Ws;
    int t = vt / Ws;
    int i = t % Hs;
    int n = t / Hs;

    // ---- mask pooling: fully unrolled, independent loads ----
    float M;
    const float* mbase = mask + (size_t)n * H_IMG * W_IMG + (size_t)(i * S) * W_IMG + j * S;
    if constexpr (S == 2) {
        float2 a = *(const float2*)(mbase);
        float2 b = *(const float2*)(mbase + W_IMG);
        M = (a.x + a.y + b.x + b.y) * 0.25f;
    } else {
        float msum = 0.0f;
        #pragma unroll
        for (int a = 0; a < S; ++a) {
            const float* mr = mbase + (size_t)a * W_IMG;
            #pragma unroll
            for (int q = 0; q < S / 4; ++q) {
                float4 fv = *(const float4*)(mr + q * 4);
                msum += (fv.x + fv.y) + (fv.z + fv.w);
            }
        }
        M = msum * (1.0f / (float)(S * S));
    }

    int y = i * S, x = j * S;
    int y0 = reflect_idx(y - 1, H_IMG), y2 = reflect_idx(y + 1, H_IMG);
    int x0 = reflect_idx(x - 1, W_IMG), x2 = reflect_idx(x + 1, W_IMG);
    constexpr size_t cstride = (size_t)Hs * Ws;

    float d2 = 0.0f;
    #pragma unroll
    for (int c = 0; c < 3; ++c) {
        const float* im = imgs + (size_t)(n * 3 + c) * H_IMG * W_IMG;
        const float* q0 = im + (size_t)y0 * W_IMG;
        const float* q1 = im + (size_t)y  * W_IMG;
        const float* q2 = im + (size_t)y2 * W_IMG;
        float p00 = q0[x0], p01 = q0[x], p02 = q0[x2];
        float p10 = q1[x0],             p12 = q1[x2];
        float p20 = q2[x0], p21 = q2[x], p22 = q2[x2];

        const float* pr = pred + ((size_t)(n * 27 + c * 9) * Hs + i) * Ws + j;
        float p[9];
        #pragma unroll
        for (int o = 0; o < 9; ++o) p[o] = pr[o * cstride];

        float gx = (p00 - p02) + 2.0f * (p10 - p12) + (p20 - p22);
        float gy = (p00 - p20) + 2.0f * (p01 - p21) + (p02 - p22);
        float mag = sqrtf(gx * gx + gy * gy);
        int bn = bin_from_g(gx, gy);
        float nrm2 = fmaf(mag, fmaf(mag, sA[bn], 2.0f * sB[bn]), Cc);
        float inv = 1.0f / fmaxf(sqrtf(nrm2), 1e-12f);

        #pragma unroll
        for (int o = 0; o < 9; ++o) {
            float h = fmaf(spwT[bn * 9 + o], mag, spb[o]) * inv;
            float dd = p[o] - h;
            d2 += dd * dd;
        }
    }

    local = M * d2 * (1.0f / 27.0f);
}

__global__ void __launch_bounds__(256) fused_kernel(
    const float* __restrict__ imgs, const float* __restrict__ mask,
    const float* __restrict__ pred0, const float* __restrict__ pred1,
    const float* __restrict__ pred2, const float* __restrict__ pred3,
    const float* __restrict__ pred4,
    const float* __restrict__ pw0, const float* __restrict__ pw1,
    const float* __restrict__ pw2, const float* __restrict__ pw3,
    const float* __restrict__ pw4,
    const float* __restrict__ pb0, const float* __restrict__ pb1,
    const float* __restrict__ pb2, const float* __restrict__ pb3,
    const float* __restrict__ pb4,
    double* __restrict__ pl, double* __restrict__ pm)
{
    __shared__ float spwT[81];   // spwT[b*9+o] = pw[o*9+b]
    __shared__ float spb[9];
    __shared__ float sA[9], sB[9], sC[1];

    int bid = blockIdx.x;
    const float* pw;  const float* pb;
    if (bid < BS16_END)      { pw = pw0; pb = pb0; }
    else if (bid < BS8_END)  { pw = pw1; pb = pb1; }
    else if (bid < BS4_END)  { pw = pw2; pb = pb2; }
    else if (bid < BS2_END)  { pw = pw3; pb = pb3; }
    else                     { pw = pw4; pb = pb4; }

    if (threadIdx.x < 81) {
        int o = threadIdx.x / 9, b = threadIdx.x % 9;
        spwT[b * 9 + o] = pw[threadIdx.x];
    }
    if (threadIdx.x < 9) spb[threadIdx.x] = pb[threadIdx.x];
    __syncthreads();
    if (threadIdx.x < 9) {
        float A = 0.0f, B = 0.0f;
        #pragma unroll
        for (int o = 0; o < 9; ++o) {
            float w = spwT[threadIdx.x * 9 + o];
            A += w * w;
            B += w * spb[o];
        }
        sA[threadIdx.x] = A;
        sB[threadIdx.x] = B;
        if (threadIdx.x == 0) {
            float Cc = 0.0f;
            #pragma unroll
            for (int o = 0; o < 9; ++o) Cc += spb[o] * spb[o];
            sC[0] = Cc;
        }
    }
    __syncthreads();
    float Cc = sC[0];

    float local = 0.0f, mlocal = 0.0f;
    if (bid < BS16_END)      scale_body<16>(bid,            imgs, mask, pred0, spwT, spb, sA, sB, Cc, local);
    else if (bid < BS8_END)  scale_body<8>(bid - BS16_END,  imgs, mask, pred1, spwT, spb, sA, sB, Cc, local);
    else if (bid < BS4_END)  scale_body<4>(bid - BS8_END,   imgs, mask, pred2, spwT, spb, sA, sB, Cc, local);
    else if (bid < BS2_END)  scale_body<2>(bid - BS4_END,   imgs, mask, pred3, spwT, spb, sA, sB, Cc, local);
    else                     s1_body4(bid - BS2_END,        imgs, mask, pred4, spwT, spb, sA, sB, Cc, local, mlocal);

    #pragma unroll
    for (int off = 32; off > 0; off >>= 1) {
        local  += __shfl_down(local,  off, 64);
        mlocal += __shfl_down(mlocal, off, 64);
    }
    __shared__ float s1[4], s2[4];
    int lane = threadIdx.x & 63, wid = threadIdx.x >> 6;
    if (lane == 0) { s1[wid] = local; s2[wid] = mlocal; }
    __syncthreads();
    if (threadIdx.x == 0) {
        pl[bid] = (double)(s1[0] + s1[1] + s1[2] + s1[3]);
        pm[bid] = (double)(s2[0] + s2[1] + s2[2] + s2[3]);
    }
}

__global__ void __launch_bounds__(256) finalize_kernel(
    const double* __restrict__ pl, const double* __restrict__ pm,
    float* __restrict__ out)
{
    double l = 0.0, m = 0.0;
    for (int idx = threadIdx.x; idx < NBLK_TOTAL; idx += 256) {
        double w = (idx < BS16_END) ? 256.0 : (idx < BS8_END) ? 64.0
                 : (idx < BS4_END) ? 16.0 : (idx < BS2_END) ? 4.0 : 1.0;
        l += w * pl[idx];
        m += pm[idx];   // nonzero only for s=1 blocks
    }
    #pragma unroll
    for (int off = 32; off > 0; off >>= 1) {
        l += __shfl_down(l, off, 64);
        m += __shfl_down(m, off, 64);
    }
    __shared__ double sl[4], sm[4];
    int lane = threadIdx.x & 63, wid = threadIdx.x >> 6;
    if (lane == 0) { sl[wid] = l; sm[wid] = m; }
    __syncthreads();
    if (threadIdx.x == 0)
        out[0] = (float)((sl[0] + sl[1] + sl[2] + sl[3]) / (sm[0] + sm[1] + sm[2] + sm[3]));
}

extern "C" void kernel_launch(void* const* d_in, const int* in_sizes, int n_in,
                              void* d_out, int out_size, void* d_ws, size_t ws_size,
                              hipStream_t stream) {
    (void)in_sizes; (void)n_in; (void)out_size; (void)ws_size;
    const float* imgs = (const float*)d_in[0];
    const float* mask = (const float*)d_in[1];
    const float* pred[5];
    const float* pw[5];
    const float* pb[5];
    for (int k = 0; k < 5; ++k) {
        pred[k] = (const float*)d_in[2 + 3 * k];
        pw[k]   = (const float*)d_in[3 + 3 * k];
        pb[k]   = (const float*)d_in[4 + 3 * k];
    }
    double* pl = (double*)d_ws;
    double* pm = pl + NBLK_TOTAL;

    fused_kernel<<<NBLK_TOTAL, 256, 0, stream>>>(
        imgs, mask,
        pred[0], pred[1], pred[2], pred[3], pred[4],
        pw[0], pw[1], pw[2], pw[3], pw[4],
        pb[0], pb[1], pb[2], pb[3], pb[4],
        pl, pm);
    finalize_kernel<<<1, 256, 0, stream>>>(pl, pm, (float*)d_out);
}